// Round 2
// baseline (187.740 us; speedup 1.0000x reference)
//
#include <hip/hip_runtime.h>
#include <math.h>

#define B_ 64
#define T_ 256
#define K_ 128
#define S_ 8
#define SEG_ 32

typedef float f32x4 __attribute__((ext_vector_type(4)));
typedef short bf16x8 __attribute__((ext_vector_type(8)));

static __device__ __forceinline__ unsigned int bf16rne(float x) {
    unsigned int u = __builtin_bit_cast(unsigned int, x);
    return (u + 0x7FFFu + ((u >> 16) & 1u)) >> 16;
}
static __device__ __forceinline__ unsigned int pkbf16(float a, float b) {
    return bf16rne(a) | (bf16rne(b) << 16);
}

// ---------------------------------------------------------------------------
// Phase 1: per-(batch,segment) transfer matrix M_s = prod diag(ey_t)*Texp.
// Wave w owns COLUMNS [32w,32w+32): column blocks evolve independently =>
// wave-private LDS, NO barriers in the main loop. A = full Texp in registers
// (128 VGPRs). Per step per wave: 8 ds_read_b128 (own 8KB block, conflict-
// free), 64 MFMA, 16 ds_write_b64. Renorm every 4 steps, wave-local shfl
// reduce, per-wave log-scale written to Cout[bs][w].
// LDS block layout: element (g,lc,j) at byte ((g*32+lc)*8+j)*2,
//   g=0..15 (rows 8g..8g+8), lc=0..31 (local col), j=0..7.
// ---------------------------------------------------------------------------
__global__ __launch_bounds__(256, 2) void crf_seg_kernel(
    const float* __restrict__ y,
    const float* __restrict__ mask,
    const float* __restrict__ trans,
    unsigned short* __restrict__ Mout,   // [B*S][128 col][128 row] bf16
    float* __restrict__ Cout)            // [B*S][4] per-wave log-scales
{
    const int bs   = blockIdx.x;
    const int b    = bs >> 3;
    const int s    = bs & 7;
    const int tid  = threadIdx.x;
    const int w    = tid >> 6;
    const int lane = tid & 63;
    const int q    = lane >> 4;
    const int ci   = lane & 15;

    __shared__ __align__(16) unsigned short Mb[4][2][4096];  // 64 KB, per-wave dbuf
    __shared__ int lenS[4];

    // ---- sequence length (mask is a contiguous 1.0 prefix) ----
    {
        float mval = mask[b * T_ + tid];
        unsigned long long bal = __ballot(mval != 0.0f);
        if (lane == 0) lenS[w] = __popcll(bal);
    }

    // ---- identity columns [32w,32w+32) into buf 0 (wave-private) ----
    #pragma unroll
    for (int p = 0; p < 8; ++p) {
        const int idx = p * 64 + lane;       // 0..511 -> (g,lc)
        const int g   = idx >> 5;
        const int lc  = idx & 31;
        const int d   = 32 * w + lc - 8 * g; // 1.0 at row 8g+j == col 32w+lc
        uint4 u4 = make_uint4(0u, 0u, 0u, 0u);
        if (d >= 0 && d < 8)
            ((unsigned int*)&u4)[d >> 1] = (d & 1) ? 0x3F800000u : 0x00003F80u;
        *(uint4*)((char*)&Mb[w][0][0] + (g * 32 + lc) * 16) = u4;
    }

    // ---- A-frags: FULL Texp, rows 16mt+ci, A[m=ci][k=8q+j] (proven layout) ----
    bf16x8 A[8][4];
    #pragma unroll
    for (int mt = 0; mt < 8; ++mt) {
        const float* tp = trans + (16 * mt + ci) * K_;
        #pragma unroll
        for (int kt = 0; kt < 4; ++kt) {
            f32x4 pv = *(const f32x4*)(tp + 32 * kt + 8 * q);
            f32x4 rv = *(const f32x4*)(tp + 32 * kt + 8 * q + 4);
            uint4 u = make_uint4(pkbf16(__expf(pv.x), __expf(pv.y)),
                                 pkbf16(__expf(pv.z), __expf(pv.w)),
                                 pkbf16(__expf(rv.x), __expf(rv.y)),
                                 pkbf16(__expf(rv.z), __expf(rv.w)));
            A[mt][kt] = __builtin_bit_cast(bf16x8, u);
        }
    }

    __syncthreads();                         // lenS only; last barrier in kernel
    const int L = lenS[0] + lenS[1] + lenS[2] + lenS[3];
    int ns = L - SEG_ * s;
    ns = ns < 0 ? 0 : (ns > SEG_ ? SEG_ : ns);

    const float* yb = y + ((size_t)b * T_ + (size_t)SEG_ * s) * K_;

    float c_acc = 0.0f;
    float spart = 0.0f;
    int cur = 0;

    for (int tt = 0; tt < ns; ++tt) {
        // B-frags from own block: (kt,nt): rows 32kt+8q+j, col 16nt+ci
        const char* rb = (const char*)&Mb[w][cur][0];
        bf16x8 Bf[4][2];
        #pragma unroll
        for (int kt = 0; kt < 4; ++kt) {
            #pragma unroll
            for (int nt = 0; nt < 2; ++nt)
                Bf[kt][nt] = *(const bf16x8*)(rb + ((kt * 4 + q) * 32 + 16 * nt + ci) * 16);
        }

        // y row (broadcast across ci; L1-hit after first wave)
        const float* yt = yb + tt * K_;
        f32x4 yv[8];
        #pragma unroll
        for (int mt = 0; mt < 8; ++mt) yv[mt] = *(const f32x4*)(yt + 16 * mt + 4 * q);

        // renorm: consume partial published at tt-1 (wave-local)
        float rinv = 1.0f;
        if (tt && (tt & 3) == 0) {
            float S = spart;
            S += __shfl_xor(S, 1);  S += __shfl_xor(S, 2);
            S += __shfl_xor(S, 4);  S += __shfl_xor(S, 8);
            S += __shfl_xor(S, 16); S += __shfl_xor(S, 32);
            rinv = __builtin_amdgcn_rcpf(S);
            c_acc += __logf(S);
            spart = 0.0f;
        }
        const bool pub = ((tt & 3) == 3);

        char* wb = (char*)&Mb[w][cur ^ 1][0];
        #pragma unroll
        for (int mt = 0; mt < 8; ++mt) {
            f32x4 C0 = {0.f, 0.f, 0.f, 0.f}, C1 = {0.f, 0.f, 0.f, 0.f};
            #pragma unroll
            for (int kt = 0; kt < 4; ++kt) {
                C0 = __builtin_amdgcn_mfma_f32_16x16x32_bf16(A[mt][kt], Bf[kt][0], C0, 0, 0, 0);
                C1 = __builtin_amdgcn_mfma_f32_16x16x32_bf16(A[mt][kt], Bf[kt][1], C1, 0, 0, 0);
            }
            f32x4 e;
            e.x = __expf(yv[mt].x) * rinv; e.y = __expf(yv[mt].y) * rinv;
            e.z = __expf(yv[mt].z) * rinv; e.w = __expf(yv[mt].w) * rinv;
            C0 *= e; C1 *= e;
            if (pub)
                spart += (C0.x + C0.y) + (C0.z + C0.w)
                       + (C1.x + C1.y) + (C1.z + C1.w);
            // write rows 16mt+4q+r, cols 16nt+ci -> g'=2mt+(q>>1), j'=4(q&1)+r
            const int gp = 2 * mt + (q >> 1);
            const int bo = 8 * (q & 1);
            uint2 d0 = make_uint2(pkbf16(C0.x, C0.y), pkbf16(C0.z, C0.w));
            uint2 d1 = make_uint2(pkbf16(C1.x, C1.y), pkbf16(C1.z, C1.w));
            *(uint2*)(wb + (gp * 32 + ci) * 16 + bo)      = d0;
            *(uint2*)(wb + (gp * 32 + 16 + ci) * 16 + bo) = d1;
        }
        cur ^= 1;
    }

    // ---- epilogue: own columns -> global [c][i] (coalesced 256B per 16 lanes)
    unsigned short* gout = Mout + ((size_t)bs << 14);
    const char* rb = (const char*)&Mb[w][cur][0];
    #pragma unroll
    for (int p = 0; p < 8; ++p) {
        const int lc = 4 * p + (lane >> 4);
        const int g  = lane & 15;
        uint4 v4 = *(const uint4*)(rb + (g * 32 + lc) * 16);
        *(uint4*)((char*)gout + (((32 * w + lc) << 7) + 8 * g) * 2) = v4;
    }
    if (lane == 0) Cout[bs * 4 + w] = c_acc;
}

// ---------------------------------------------------------------------------
// Phase 2: combine. One block per batch. Thread (cg,ig) owns c in [8cg,8cg+8),
// i in [8ig,8ig+8). Matrix chunks prefetched from global into ping-pong reg
// banks (static indexing), vectorized bf16 unpack + FMA, two-pass LDS reduce.
// Per-wave column-block scales folded into u before each matvec.
// ---------------------------------------------------------------------------
__global__ __launch_bounds__(256) void crf_comb_kernel(
    const unsigned short* __restrict__ Mseg,
    const float* __restrict__ Cseg,      // [B*S][4]
    float* __restrict__ out)
{
    const int b   = blockIdx.x;
    const int tid = threadIdx.x;
    const int cg  = tid >> 4;
    const int ig  = tid & 15;

    __shared__ float uSc[K_];
    __shared__ __align__(16) float tmp[16][K_];
    __shared__ float redS[4];

    if (tid < K_) uSc[tid] = (tid == 2) ? 1.0f : 0.0f;   // e_SOS

    float c_tot = 0.0f;
    uint4 RA[8], RB[8];
    {
        const unsigned short* M0 = Mseg + ((size_t)(b * S_) << 14);
        #pragma unroll
        for (int r = 0; r < 8; ++r)
            RA[r] = *(const uint4*)(M0 + ((8 * cg + r) << 7) + 8 * ig);
    }
    __syncthreads();

    #pragma unroll
    for (int s = 0; s < S_; ++s) {
        const uint4* Rcur = (s & 1) ? RB : RA;           // s is compile-time
        uint4*       Rnxt = (s & 1) ? RA : RB;
        if (s + 1 < S_) {
            const unsigned short* Mn = Mseg + ((size_t)(b * S_ + s + 1) << 14);
            #pragma unroll
            for (int r = 0; r < 8; ++r)
                Rnxt[r] = *(const uint4*)(Mn + ((8 * cg + r) << 7) + 8 * ig);
        }

        const float g0 = Cseg[(b * S_ + s) * 4 + 0];
        const float g1 = Cseg[(b * S_ + s) * 4 + 1];
        const float g2 = Cseg[(b * S_ + s) * 4 + 2];
        const float g3 = Cseg[(b * S_ + s) * 4 + 3];
        const float cmax = fmaxf(fmaxf(g0, g1), fmaxf(g2, g3));
        const float gw = (cg < 8) ? ((cg < 4) ? g0 : g1) : ((cg < 12) ? g2 : g3);
        const float fw = __expf(gw - cmax);

        float acc[8];
        #pragma unroll
        for (int e = 0; e < 8; ++e) acc[e] = 0.0f;
        #pragma unroll
        for (int r = 0; r < 8; ++r) {
            const float ub = uSc[8 * cg + r] * fw;
            const uint4 m4 = Rcur[r];
            const unsigned int* mw_ = (const unsigned int*)&m4;
            #pragma unroll
            for (int h2 = 0; h2 < 4; ++h2) {
                const unsigned int u = mw_[h2];
                acc[2 * h2]     += __builtin_bit_cast(float, u << 16) * ub;
                acc[2 * h2 + 1] += __builtin_bit_cast(float, u & 0xFFFF0000u) * ub;
            }
        }
        *(f32x4*)&tmp[cg][8 * ig]     = *(const f32x4*)&acc[0];
        *(f32x4*)&tmp[cg][8 * ig + 4] = *(const f32x4*)&acc[4];
        __syncthreads();

        float un = 0.0f;
        if (tid < K_) {
            #pragma unroll
            for (int c2 = 0; c2 < 16; ++c2) un += tmp[c2][tid];
        }
        float ps = un;
        ps += __shfl_xor(ps, 1);  ps += __shfl_xor(ps, 2);
        ps += __shfl_xor(ps, 4);  ps += __shfl_xor(ps, 8);
        ps += __shfl_xor(ps, 16); ps += __shfl_xor(ps, 32);
        if ((tid & 63) == 0) redS[tid >> 6] = ps;
        __syncthreads();
        const float total = (redS[0] + redS[1]) + (redS[2] + redS[3]);
        const float rt = 1.0f / total;
        if (tid < K_) uSc[tid] = un * rt;
        c_tot += __logf(total) + cmax;
        __syncthreads();
    }

    if (tid == 0) out[b] = c_tot;
}

extern "C" void kernel_launch(void* const* d_in, const int* in_sizes, int n_in,
                              void* d_out, int out_size, void* d_ws, size_t ws_size,
                              hipStream_t stream) {
    const float* y     = (const float*)d_in[0];   // (B, T, K) fp32
    const float* mask  = (const float*)d_in[1];   // (B, T)    fp32 0/1
    const float* trans = (const float*)d_in[2];   // (K, K)    fp32
    float* out = (float*)d_out;                   // (B,)      fp32

    unsigned short* Mws = (unsigned short*)d_ws;                       // 16.78 MB
    float* Cws = (float*)((char*)d_ws + (size_t)B_ * S_ * K_ * K_ * 2);

    crf_seg_kernel<<<B_ * S_, 256, 0, stream>>>(y, mask, trans, Mws, Cws);
    crf_comb_kernel<<<B_, 256, 0, stream>>>(Mws, Cws, out);
}